// Round 15
// baseline (194.625 us; speedup 1.0000x reference)
//
#include <hip/hip_runtime.h>

#define EPS 1e-8f

using short8 = __attribute__((ext_vector_type(8))) short;
using f32x16 = __attribute__((ext_vector_type(16))) float;
typedef unsigned short u16;

#define WAITV(N) asm volatile("s_waitcnt vmcnt(" #N ")" ::: "memory")
#define BARRIER() do { __builtin_amdgcn_s_barrier(); \
                       asm volatile("" ::: "memory"); } while (0)

__device__ __forceinline__ u16 f2bf(float f) {
    union { float f; unsigned u; } v; v.f = f;
    unsigned u = v.u;
    return (u16)((u + 0x7FFFu + ((u >> 16) & 1u)) >> 16);
}

__device__ __forceinline__ void g2l16(const void* gsrc, void* ldst) {
    __builtin_amdgcn_global_load_lds(
        (const __attribute__((address_space(1))) unsigned int*)gsrc,
        (__attribute__((address_space(3))) unsigned int*)ldst, 16, 0, 0);
}

// ---------------- kernel 1: style[b][i] = dot(w[b], affine_w[i]) + affine_b[i] + 1
__global__ void style_kernel(const float* __restrict__ w,        // [8][512]
                             const float* __restrict__ affine_w, // [256][512]
                             const float* __restrict__ affine_b, // [256]
                             float* __restrict__ style) {        // [8][256]
    int b = blockIdx.x;
    int i = threadIdx.x;
    __shared__ float wb[512];
    for (int z = threadIdx.x; z < 512; z += 256) wb[z] = w[b * 512 + z];
    __syncthreads();
    const float* aw = affine_w + i * 512;
    float acc = 0.f;
#pragma unroll 4
    for (int z = 0; z < 512; z += 4) {
        float4 a4 = *reinterpret_cast<const float4*>(aw + z);
        acc += a4.x * wb[z] + a4.y * wb[z + 1] + a4.z * wb[z + 2] + a4.w * wb[z + 3];
    }
    style[b * 256 + i] = acc + affine_b[i] + 1.0f;
}

// ---------------- kernel 2: PREP = modw (blocks 0..2047) + xform (blocks 2048..18431)
// modw: modulate+demodulate, pack bf16 wgt [b][t9][g32][o256][j8].
// xform: x fp32 [8][256][128][128] -> bf16 xb [8][32][128][128][8].
// Independent work merged into one dispatch: modw's latency-bound blocks hide
// inside xform's HBM-bound shadow (saves a ~8-12us serialized dispatch).
__global__ __launch_bounds__(256) void prep_kernel(
    const float* __restrict__ weight, // [256][256][3][3]
    const float* __restrict__ style,  // [8][256]
    u16* __restrict__ wgt,
    const float* __restrict__ x,
    u16* __restrict__ xb) {
    int blk = blockIdx.x;
    if (blk < 2048) { // ---- modw body
        int b = blk >> 8;
        int o = blk & 255;
        int ic = threadIdx.x;
        float s = style[b * 256 + ic];
        const float* wp = weight + (size_t)(o * 256 + ic) * 9;
        float m[9];
        float ss = 0.f;
#pragma unroll
        for (int t = 0; t < 9; ++t) { m[t] = wp[t] * s; ss += m[t] * m[t]; }
#pragma unroll
        for (int off = 32; off > 0; off >>= 1) ss += __shfl_down(ss, off);
        __shared__ float part[4];
        int lane = threadIdx.x & 63, wid = threadIdx.x >> 6;
        if (lane == 0) part[wid] = ss;
        __syncthreads();
        float denom = rsqrtf(part[0] + part[1] + part[2] + part[3] + EPS);
        int g = ic >> 3, j = ic & 7;
#pragma unroll
        for (int t = 0; t < 9; ++t) {
            size_t idx = ((((size_t)(b * 9 + t) * 32 + g) * 256 + o) << 3) + j;
            wgt[idx] = f2bf(m[t] * denom);
        }
    } else { // ---- xform body
        int s = (blk - 2048) * 256 + threadIdx.x; // (b,g,h,w)
        int w = s & 127, h = (s >> 7) & 127, g = (s >> 14) & 31, b = s >> 19;
        const float* xp = x + (((size_t)(b * 256 + g * 8) * 128 + h) * 128 + w);
        union { u16 u[8]; short8 v; } pk;
#pragma unroll
        for (int j = 0; j < 8; ++j) pk.u[j] = f2bf(xp[(size_t)j * 16384]);
        *reinterpret_cast<short8*>(&xb[(size_t)s * 8]) = pk.v;
    }
}

// ---------------- kernel 3: implicit-GEMM conv, 32x32x16 MFMA (R9 structure)
// block = (b, ot, ht): 128 o x (2 rows x 128 w), 256 threads (4 waves), 2 blocks/CU.
// A: global->VGPR per wave (L2-resident), DISTANCE-2 prefetch via 3 static slots
//    af[(t)%3] (compile-time indices under the unrolled tap loop; 9%3==0 keeps
//    phase alignment across chunks). At tap t: consume af[t%3], load tap t+2
//    into af[(t+2)%3] -> ~2 taps (~1000 cyc) of L2-latency cover.
// X: LDS double-buffer; chunk c+1 staged via global_load_lds at t==0 (after that
//    tap's loadA in the vmcnt FIFO). Chunk end: WAITV(32) drains exactly the 8
//    X g2l16 (8 A-stages x 4 loads remain in flight) + barrier. No vmcnt(0).
__global__ __launch_bounds__(256, 2) void conv_kernel(
    const u16* __restrict__ xb,  // [8][32][128][128][8] bf16
    const u16* __restrict__ wgt, // [8][9][32][256][8] bf16
    float* __restrict__ out) {   // [8][256][128][128]

    __shared__ __align__(16) u16 Xs[2][4][4][130][8]; // 66560 B [buf][row][g][w130][j8]
    __shared__ __align__(16) u16 trash[1024];         // OOB-row sink

    int bid = blockIdx.x;
    int swz = (bid & 7) * 128 + (bid >> 3); // grid 1024 = 8*128, bijective
    int ht = swz & 63, ot = (swz >> 6) & 1, b = swz >> 7;
    int h0 = ht * 2;

    int tid = threadIdx.x, lane = tid & 63, wid = tid >> 6;
    int wm = wid >> 1, wr = wid & 1; // wave -> (o half 64, row)
    int l31 = lane & 31, lh = lane >> 5;

    int hr = h0 + wid - 1;
    bool hValid = ((unsigned)hr < 128u);
    int hc = hValid ? hr : 0;

    // per-lane A base: (b, t=0, g=lh, o = ot*128 + wm*64 + l31)
    const u16* aBase = wgt + ((size_t)(b * 9) * 32 * 256 +
                              (size_t)(lh * 256 + ot * 128 + wm * 64 + l31)) * 8;

    auto loadA = [&](short8 dst[2][2], int c, int t) {
#pragma unroll
        for (int kk = 0; kk < 2; ++kk)
#pragma unroll
            for (int mi = 0; mi < 2; ++mi)
                dst[kk][mi] = *reinterpret_cast<const short8*>(
                    aBase + (size_t)(((t * 32) + c * 4 + kk * 2) * 256 + mi * 32) * 8);
    };
    auto stageX = [&](int c1, int bx) { // wave wid stages row wid: 8 x 1KB g2l16
#pragma unroll
        for (int k = 0; k < 8; ++k) {
            int g = k >> 1, half = k & 1;
            const u16* src = xb +
                ((((size_t)(b * 32 + c1 * 4 + g)) * 128 + hc) * 128 + half * 64 + lane) * 8;
            void* dst = hValid ? (void*)&Xs[bx][wid][g][1 + half * 64][0] : (void*)trash;
            g2l16(src, dst);
        }
    };

    // zero both X buffers (borders + OOB rows stay zero forever)
    {
        short8 z = {0, 0, 0, 0, 0, 0, 0, 0};
        short8* p0 = reinterpret_cast<short8*>(&Xs[0][0][0][0][0]);
        for (int i = tid; i < 4160; i += 256) p0[i] = z;
    }
    __syncthreads();

    short8 af[3][2][2];    // 3-slot A rotation, statically indexed
    stageX(0, 0);          // X chunk 0 (oldest in FIFO)
    loadA(af[0], 0, 0);
    loadA(af[1], 0, 1);
    WAITV(8);              // drain X0; leave A(0),A(1)
    BARRIER();

    f32x16 acc[2][4] = {};

    for (int c = 0; c < 8; ++c) {
        int buf = c & 1;
#pragma unroll
        for (int t = 0; t < 9; ++t) {
            // distance-2 A prefetch (skip last two taps of last chunk)
            if (!(c == 7 && t >= 7)) {
                int tt = t + 2, nc = c, nt = tt;
                if (tt > 8) { nc = c + 1; nt = tt - 9; }
                loadA(af[(t + 2) % 3], nc, nt);
            }
            if (t == 0 && c < 7) stageX(c + 1, buf ^ 1);

            int kh = t / 3, kw = t - kh * 3;
            short8 bx8[2][4];
#pragma unroll
            for (int kk = 0; kk < 2; ++kk)
#pragma unroll
                for (int ni = 0; ni < 4; ++ni)
                    bx8[kk][ni] = *reinterpret_cast<const short8*>(
                        &Xs[buf][wr + kh][kk * 2 + lh][ni * 32 + l31 + kw][0]);
            __builtin_amdgcn_s_setprio(1);
#pragma unroll
            for (int mi = 0; mi < 2; ++mi)
#pragma unroll
                for (int ni = 0; ni < 4; ++ni)
#pragma unroll
                    for (int kk = 0; kk < 2; ++kk)
                        acc[mi][ni] = __builtin_amdgcn_mfma_f32_32x32x16_bf16(
                            af[t % 3][kk][mi], bx8[kk][ni], acc[mi][ni], 0, 0, 0);
            __builtin_amdgcn_s_setprio(0);
        }
        // chunk boundary: drain exactly the 8 X g2l16; 8 A-stages (32 loads) stay
        if (c < 7) { WAITV(32); BARRIER(); }
    }

    // epilogue: C/D 32x32 layout col=lane&31 (w), row=(reg&3)+8*(reg>>2)+4*(lane>>5) (o)
    int h = h0 + wr;
#pragma unroll
    for (int mi = 0; mi < 2; ++mi) {
        int ob = ot * 128 + wm * 64 + mi * 32 + 4 * lh;
#pragma unroll
        for (int ni = 0; ni < 4; ++ni) {
            int w_ = ni * 32 + l31;
#pragma unroll
            for (int reg = 0; reg < 16; ++reg) {
                int o = ob + (reg & 3) + 8 * (reg >> 2);
                out[(((size_t)(b * 256 + o) * 128 + h) * 128) + w_] = acc[mi][ni][reg];
            }
        }
    }
}

extern "C" void kernel_launch(void* const* d_in, const int* in_sizes, int n_in,
                              void* d_out, int out_size, void* d_ws, size_t ws_size,
                              hipStream_t stream) {
    const float* x        = (const float*)d_in[0];
    const float* w        = (const float*)d_in[1];
    const float* weight   = (const float*)d_in[2];
    const float* affine_w = (const float*)d_in[3];
    const float* affine_b = (const float*)d_in[4];
    float* out = (float*)d_out;

    float* style = (float*)d_ws;                                   // 8 KB
    u16* wgt = (u16*)((char*)d_ws + 8192);                         // 9.44 MB
    u16* xbuf = (u16*)((char*)d_ws + 8192 + 9437184);              // 64 MB

    style_kernel<<<8, 256, 0, stream>>>(w, affine_w, affine_b, style);
    prep_kernel<<<18432, 256, 0, stream>>>(weight, style, wgt, x, xbuf);
    conv_kernel<<<1024, 256, 0, stream>>>(xbuf, wgt, out);
}

// Round 16
// 178.626 us; speedup vs baseline: 1.0896x; 1.0896x over previous
//
#include <hip/hip_runtime.h>
#include <hip/hip_bf16.h>

#define EPS 1e-8f

using short8 = __attribute__((ext_vector_type(8))) short;
using f32x16 = __attribute__((ext_vector_type(16))) float;
typedef unsigned short u16;

#define BARRIER() do { __builtin_amdgcn_s_barrier(); \
                       asm volatile("" ::: "memory"); } while (0)
#define LGKM0() asm volatile("s_waitcnt lgkmcnt(0)" ::: "memory")

__device__ __forceinline__ u16 f2bf(float f) {
    union { float f; unsigned u; } v; v.f = f;
    unsigned u = v.u;
    return (u16)((u + 0x7FFFu + ((u >> 16) & 1u)) >> 16);
}

// ---------------- kernel 1: style[b][i] = dot(w[b], affine_w[i]) + affine_b[i] + 1
__global__ void style_kernel(const float* __restrict__ w,        // [8][512]
                             const float* __restrict__ affine_w, // [256][512]
                             const float* __restrict__ affine_b, // [256]
                             float* __restrict__ style) {        // [8][256]
    int b = blockIdx.x;
    int i = threadIdx.x;
    __shared__ float wb[512];
    for (int z = threadIdx.x; z < 512; z += 256) wb[z] = w[b * 512 + z];
    __syncthreads();
    const float* aw = affine_w + i * 512;
    float acc = 0.f;
#pragma unroll 4
    for (int z = 0; z < 512; z += 4) {
        float4 a4 = *reinterpret_cast<const float4*>(aw + z);
        acc += a4.x * wb[z] + a4.y * wb[z + 1] + a4.z * wb[z + 2] + a4.w * wb[z + 3];
    }
    style[b * 256 + i] = acc + affine_b[i] + 1.0f;
}

// ---------------- kernel 2: modulate + demodulate, pack bf16 weights
// wgt layout: bf16 [b][t(9)][g(32)][o(256)][j(8)], ic = g*8 + j
__global__ void modw_kernel(const float* __restrict__ weight, // [256][256][3][3]
                            const float* __restrict__ style,  // [8][256]
                            u16* __restrict__ wgt) {
    int b = blockIdx.x >> 8;
    int o = blockIdx.x & 255;
    int ic = threadIdx.x; // 256 threads
    float s = style[b * 256 + ic];
    const float* wp = weight + (size_t)(o * 256 + ic) * 9;
    float m[9];
    float ss = 0.f;
#pragma unroll
    for (int t = 0; t < 9; ++t) { m[t] = wp[t] * s; ss += m[t] * m[t]; }
#pragma unroll
    for (int off = 32; off > 0; off >>= 1) ss += __shfl_down(ss, off);
    __shared__ float part[4];
    int lane = threadIdx.x & 63, wid = threadIdx.x >> 6;
    if (lane == 0) part[wid] = ss;
    __syncthreads();
    float denom = rsqrtf(part[0] + part[1] + part[2] + part[3] + EPS);
    int g = ic >> 3, j = ic & 7;
#pragma unroll
    for (int t = 0; t < 9; ++t) {
        size_t idx = ((((size_t)(b * 9 + t) * 32 + g) * 256 + o) << 3) + j;
        wgt[idx] = f2bf(m[t] * denom);
    }
}

// ---------------- kernel 3: fused implicit-GEMM conv (xform folded, float2 gather)
// block = (b, ot, ht): 128 o x (2 rows x 128 w), 256 threads (4 waves), 2 blocks/CU.
// A: global->VGPR per wave (L2-resident), 1-tap prefetch afC/afN.
// X: fp32 x gathered with FLOAT2 loads (8 issues per (row,g) unit vs 16 scalar):
//    lane loads float2 at w=2*lane for j=0..7, so it holds BOTH w=2l and w=2l+1
//    complete j-octets -> cvt + two ds_write_b128. 16 units (row4 x g4), 4 per
//    wave (wave wid stages row wid): issued tap t (t<4), written tap t+1
//    (distance-1: fused tap ~2650cyc > 900cyc HBM; R12/R13 showed d1==d2).
//    Single 16-reg slot: write(t-1) then issue(t) reuses it (program order).
// Chunk boundary: lgkmcnt(0) + barrier. OOB rows never written (zeros persist).
__global__ __launch_bounds__(256, 2) void conv_kernel(
    const float* __restrict__ x,  // [8][256][128][128] fp32
    const u16* __restrict__ wgt,  // [8][9][32][256][8] bf16
    float* __restrict__ out) {    // [8][256][128][128]

    __shared__ __align__(16) u16 Xs[2][4][4][130][8]; // 66560 B [buf][row][g][w130][j8]

    int bid = blockIdx.x;
    int swz = (bid & 7) * 128 + (bid >> 3); // grid 1024 = 8*128, bijective
    int ht = swz & 63, ot = (swz >> 6) & 1, b = swz >> 7;
    int h0 = ht * 2;

    int tid = threadIdx.x, lane = tid & 63, wid = tid >> 6;
    int wm = wid >> 1, wr = wid & 1; // wave -> (o half 64, row)
    int l31 = lane & 31, lh = lane >> 5;

    int hr = h0 + wid - 1;
    bool hValid = ((unsigned)hr < 128u);
    int hc = hValid ? hr : 0;

    // per-lane bases
    const u16* aBase = wgt + ((size_t)(b * 9) * 32 * 256 +
                              (size_t)(lh * 256 + ot * 128 + wm * 64 + l31)) * 8;
    const float* xBase = x + ((size_t)(b * 256) * 128 + hc) * 128 + 2 * lane;

    auto loadA = [&](short8 dst[2][2], int c, int t) {
#pragma unroll
        for (int kk = 0; kk < 2; ++kk)
#pragma unroll
            for (int mi = 0; mi < 2; ++mi)
                dst[kk][mi] = *reinterpret_cast<const short8*>(
                    aBase + (size_t)(((t * 32) + c * 4 + kk * 2) * 256 + mi * 32) * 8);
    };
    // unit g of chunk c1, row = wid: 8 float2 loads (j=0..7)
    auto issueX = [&](float* dst, int c1, int g) {
        const float* sp = xBase + (size_t)(c1 * 32 + g * 8) * 16384;
#pragma unroll
        for (int j = 0; j < 8; ++j)
            *reinterpret_cast<float2*>(&dst[j * 2]) =
                *reinterpret_cast<const float2*>(sp + (size_t)j * 16384);
    };
    auto writeX = [&](const float* src, int g, int bx) {
        union { u16 u[8]; short8 v; } pk0, pk1;
#pragma unroll
        for (int j = 0; j < 8; ++j) {
            __hip_bfloat16 h0b = __float2bfloat16(src[j * 2]);
            __hip_bfloat16 h1b = __float2bfloat16(src[j * 2 + 1]);
            pk0.u[j] = reinterpret_cast<u16&>(h0b);
            pk1.u[j] = reinterpret_cast<u16&>(h1b);
        }
        *reinterpret_cast<short8*>(&Xs[bx][wid][g][1 + 2 * lane][0]) = pk0.v;
        *reinterpret_cast<short8*>(&Xs[bx][wid][g][2 + 2 * lane][0]) = pk1.v;
    };

    // zero both X buffers (borders + OOB rows stay zero forever)
    {
        short8 z = {0, 0, 0, 0, 0, 0, 0, 0};
        short8* p0 = reinterpret_cast<short8*>(&Xs[0][0][0][0][0]);
        for (int i = tid; i < 4160; i += 256) p0[i] = z;
    }
    __syncthreads();

    short8 afC[2][2], afN[2][2];
    // prologue: stage chunk 0 into buf 0 (4 units, all issued then all written)
    if (hValid) {
        float xg0[4][16];
#pragma unroll
        for (int g = 0; g < 4; ++g) issueX(xg0[g], 0, g);
#pragma unroll
        for (int g = 0; g < 4; ++g) writeX(xg0[g], g, 0);
    }
    loadA(afC, 0, 0);
    LGKM0();
    BARRIER();

    f32x16 acc[2][4] = {};
    float xg[16]; // single staging slot: write(t-1) then issue(t) reuses it

    for (int c = 0; c < 8; ++c) {
        int buf = c & 1;
        bool stage = (c < 7) && hValid;
#pragma unroll
        for (int t = 0; t < 9; ++t) {
            bool lastTap = (c == 7 && t == 8);
            if (!lastTap)
                loadA(afN, t < 8 ? c : c + 1, t < 8 ? t + 1 : 0);
            if (stage) {
                if (t >= 1 && t < 5) writeX(xg, t - 1, buf ^ 1); // unit t-1
                if (t < 4)           issueX(xg, c + 1, t);       // unit t
            }

            int kh = t / 3, kw = t - kh * 3;
            short8 bx8[2][4];
#pragma unroll
            for (int kk = 0; kk < 2; ++kk)
#pragma unroll
                for (int ni = 0; ni < 4; ++ni)
                    bx8[kk][ni] = *reinterpret_cast<const short8*>(
                        &Xs[buf][wr + kh][kk * 2 + lh][ni * 32 + l31 + kw][0]);
            __builtin_amdgcn_s_setprio(1);
#pragma unroll
            for (int mi = 0; mi < 2; ++mi)
#pragma unroll
                for (int ni = 0; ni < 4; ++ni)
#pragma unroll
                    for (int kk = 0; kk < 2; ++kk)
                        acc[mi][ni] = __builtin_amdgcn_mfma_f32_32x32x16_bf16(
                            afC[kk][mi], bx8[kk][ni], acc[mi][ni], 0, 0, 0);
            __builtin_amdgcn_s_setprio(0);

            if (!lastTap) {
#pragma unroll
                for (int k2 = 0; k2 < 2; ++k2)
#pragma unroll
                    for (int mi = 0; mi < 2; ++mi)
                        afC[k2][mi] = afN[k2][mi];
            }
        }
        if (c < 7) { LGKM0(); BARRIER(); } // ds_writes of chunk c+1 visible block-wide
    }

    // epilogue: C/D 32x32 layout col=lane&31 (w), row=(reg&3)+8*(reg>>2)+4*(lane>>5) (o)
    int h = h0 + wr;
#pragma unroll
    for (int mi = 0; mi < 2; ++mi) {
        int ob = ot * 128 + wm * 64 + mi * 32 + 4 * lh;
#pragma unroll
        for (int ni = 0; ni < 4; ++ni) {
            int w_ = ni * 32 + l31;
#pragma unroll
            for (int reg = 0; reg < 16; ++reg) {
                int o = ob + (reg & 3) + 8 * (reg >> 2);
                out[(((size_t)(b * 256 + o) * 128 + h) * 128) + w_] = acc[mi][ni][reg];
            }
        }
    }
}

extern "C" void kernel_launch(void* const* d_in, const int* in_sizes, int n_in,
                              void* d_out, int out_size, void* d_ws, size_t ws_size,
                              hipStream_t stream) {
    const float* x        = (const float*)d_in[0];
    const float* w        = (const float*)d_in[1];
    const float* weight   = (const float*)d_in[2];
    const float* affine_w = (const float*)d_in[3];
    const float* affine_b = (const float*)d_in[4];
    float* out = (float*)d_out;

    float* style = (float*)d_ws;                                   // 8 KB
    u16* wgt = (u16*)((char*)d_ws + 8192);                         // 9.44 MB

    style_kernel<<<8, 256, 0, stream>>>(w, affine_w, affine_b, style);
    modw_kernel<<<2048, 256, 0, stream>>>(weight, style, wgt);
    conv_kernel<<<1024, 256, 0, stream>>>(x, wgt, out);
}

// Round 17
// 173.585 us; speedup vs baseline: 1.1212x; 1.0290x over previous
//
#include <hip/hip_runtime.h>
#include <hip/hip_bf16.h>

#define EPS 1e-8f

using short8 = __attribute__((ext_vector_type(8))) short;
using f32x16 = __attribute__((ext_vector_type(16))) float;
typedef unsigned short u16;

#define BARRIER() do { __builtin_amdgcn_s_barrier(); \
                       asm volatile("" ::: "memory"); } while (0)
#define LGKM0() asm volatile("s_waitcnt lgkmcnt(0)" ::: "memory")

__device__ __forceinline__ u16 f2bf(float f) {
    union { float f; unsigned u; } v; v.f = f;
    unsigned u = v.u;
    return (u16)((u + 0x7FFFu + ((u >> 16) & 1u)) >> 16);
}

// ---------------- kernel 1: style[b][i] = dot(w[b], affine_w[i]) + affine_b[i] + 1
__global__ void style_kernel(const float* __restrict__ w,        // [8][512]
                             const float* __restrict__ affine_w, // [256][512]
                             const float* __restrict__ affine_b, // [256]
                             float* __restrict__ style) {        // [8][256]
    int b = blockIdx.x;
    int i = threadIdx.x;
    __shared__ float wb[512];
    for (int z = threadIdx.x; z < 512; z += 256) wb[z] = w[b * 512 + z];
    __syncthreads();
    const float* aw = affine_w + i * 512;
    float acc = 0.f;
#pragma unroll 4
    for (int z = 0; z < 512; z += 4) {
        float4 a4 = *reinterpret_cast<const float4*>(aw + z);
        acc += a4.x * wb[z] + a4.y * wb[z + 1] + a4.z * wb[z + 2] + a4.w * wb[z + 3];
    }
    style[b * 256 + i] = acc + affine_b[i] + 1.0f;
}

// ---------------- kernel 2: modulate + demodulate, pack bf16 weights
// wgt layout: bf16 [b][t(9)][g(32)][o(256)][j(8)], ic = g*8 + j
__global__ void modw_kernel(const float* __restrict__ weight, // [256][256][3][3]
                            const float* __restrict__ style,  // [8][256]
                            u16* __restrict__ wgt) {
    int b = blockIdx.x >> 8;
    int o = blockIdx.x & 255;
    int ic = threadIdx.x; // 256 threads
    float s = style[b * 256 + ic];
    const float* wp = weight + (size_t)(o * 256 + ic) * 9;
    float m[9];
    float ss = 0.f;
#pragma unroll
    for (int t = 0; t < 9; ++t) { m[t] = wp[t] * s; ss += m[t] * m[t]; }
#pragma unroll
    for (int off = 32; off > 0; off >>= 1) ss += __shfl_down(ss, off);
    __shared__ float part[4];
    int lane = threadIdx.x & 63, wid = threadIdx.x >> 6;
    if (lane == 0) part[wid] = ss;
    __syncthreads();
    float denom = rsqrtf(part[0] + part[1] + part[2] + part[3] + EPS);
    int g = ic >> 3, j = ic & 7;
#pragma unroll
    for (int t = 0; t < 9; ++t) {
        size_t idx = ((((size_t)(b * 9 + t) * 32 + g) * 256 + o) << 3) + j;
        wgt[idx] = f2bf(m[t] * denom);
    }
}

// ---------------- kernel 3: fused implicit-GEMM conv (float4 gather + permlane swap)
// block = (b, ot, ht): 128 o x (2 rows x 128 w), 256 threads (4 waves), 2 blocks/CU.
// A: global->VGPR per wave (L2-resident), 1-tap prefetch afC/afN.
// X staging per (row,g) unit: FOUR float4 issues (vs 8 float2 in R16):
//    issue i: lanes 0-31 read j-plane i, lanes 32-63 read j-plane i+4, both at
//    w = 4*(lane&31) (two coalesced 512B streams per instruction).
//    cvt-pack -> X[k][d] dwords (k = w sub-index 0..3, d = j-pair within half).
//    v_permlane32_swap_b32 exchanges octet halves: lo-lanes end with full
//    j-octets for w=4l,4l+1; hi-lanes for w=4l+2,4l+3 -> two ds_write_b128
//    (write-slot pattern identical to R16: odd slots then even slots).
//    Unit g staged at tap t=g (issue), written at tap t+1. Single 16-reg slot.
// Chunk boundary: lgkmcnt(0) + barrier. OOB rows never written (zeros persist).
__global__ __launch_bounds__(256, 2) void conv_kernel(
    const float* __restrict__ x,  // [8][256][128][128] fp32
    const u16* __restrict__ wgt,  // [8][9][32][256][8] bf16
    float* __restrict__ out) {    // [8][256][128][128]

    __shared__ __align__(16) u16 Xs[2][4][4][130][8]; // 66560 B [buf][row][g][w130][j8]

    int bid = blockIdx.x;
    int swz = (bid & 7) * 128 + (bid >> 3); // grid 1024 = 8*128, bijective
    int ht = swz & 63, ot = (swz >> 6) & 1, b = swz >> 7;
    int h0 = ht * 2;

    int tid = threadIdx.x, lane = tid & 63, wid = tid >> 6;
    int wm = wid >> 1, wr = wid & 1; // wave -> (o half 64, row)
    int l31 = lane & 31, lh = lane >> 5;
    int lw = lane & 31, hi = lane >> 5;     // staging lane split
    int jbase = hi * 4;                      // lanes>=32 handle j-planes 4..7
    int koff = hi * 2;                       // w sub-index base after swap

    int hr = h0 + wid - 1;
    bool hValid = ((unsigned)hr < 128u);
    int hc = hValid ? hr : 0;

    // per-lane bases
    const u16* aBase = wgt + ((size_t)(b * 9) * 32 * 256 +
                              (size_t)(lh * 256 + ot * 128 + wm * 64 + l31)) * 8;
    const float* xSt = x + (((size_t)(b * 256 + jbase)) * 128 + hc) * 128 + 4 * lw;

    auto loadA = [&](short8 dst[2][2], int c, int t) {
#pragma unroll
        for (int kk = 0; kk < 2; ++kk)
#pragma unroll
            for (int mi = 0; mi < 2; ++mi)
                dst[kk][mi] = *reinterpret_cast<const short8*>(
                    aBase + (size_t)(((t * 32) + c * 4 + kk * 2) * 256 + mi * 32) * 8);
    };
    // unit g of chunk c1, row = wid: 4 float4 issues (j-planes jbase..jbase+3)
    auto issueX = [&](float* dst, int c1, int g) {
        const float* sp = xSt + (size_t)(c1 * 32 + g * 8) * 16384;
#pragma unroll
        for (int i = 0; i < 4; ++i)
            *reinterpret_cast<float4*>(&dst[i * 4]) =
                *reinterpret_cast<const float4*>(sp + (size_t)i * 16384);
    };
    auto writeX = [&](const float* src, int g, int bx) {
        // pack: X[k][d] = bf16x2 of (F_{2d}[k], F_{2d+1}[k]); F_i[k] = src[i*4+k]
        unsigned X[4][2];
#pragma unroll
        for (int k = 0; k < 4; ++k)
#pragma unroll
            for (int d = 0; d < 2; ++d) {
                __hip_bfloat16 b0 = __float2bfloat16(src[(2 * d) * 4 + k]);
                __hip_bfloat16 b1 = __float2bfloat16(src[(2 * d + 1) * 4 + k]);
                X[k][d] = (unsigned)reinterpret_cast<u16&>(b0) |
                          ((unsigned)reinterpret_cast<u16&>(b1) << 16);
            }
        // half-exchange: after swap(A=X[ka][d], B=X[ka+2][d]):
        //   A' = lo: LO_ka | hi: LO_{ka+2};  B' = lo: HI_ka | hi: HI_{ka+2}
        unsigned a00 = X[0][0], c00 = X[2][0];
        unsigned a01 = X[0][1], c01 = X[2][1];
        unsigned a10 = X[1][0], c10 = X[3][0];
        unsigned a11 = X[1][1], c11 = X[3][1];
        asm volatile("v_permlane32_swap_b32 %0, %1" : "+v"(a00), "+v"(c00));
        asm volatile("v_permlane32_swap_b32 %0, %1" : "+v"(a01), "+v"(c01));
        asm volatile("v_permlane32_swap_b32 %0, %1" : "+v"(a10), "+v"(c10));
        asm volatile("v_permlane32_swap_b32 %0, %1" : "+v"(a11), "+v"(c11));
        union { unsigned d[4]; short8 v; } oA, oB;
        oA.d[0] = a00; oA.d[1] = a01; oA.d[2] = c00; oA.d[3] = c01; // octet w=4lw+koff
        oB.d[0] = a10; oB.d[1] = a11; oB.d[2] = c10; oB.d[3] = c11; // octet w=4lw+koff+1
        int slotA = 1 + 4 * lw + koff;
        *reinterpret_cast<short8*>(&Xs[bx][wid][g][slotA][0])     = oA.v;
        *reinterpret_cast<short8*>(&Xs[bx][wid][g][slotA + 1][0]) = oB.v;
    };

    // zero both X buffers (borders + OOB rows stay zero forever)
    {
        short8 z = {0, 0, 0, 0, 0, 0, 0, 0};
        short8* p0 = reinterpret_cast<short8*>(&Xs[0][0][0][0][0]);
        for (int i = tid; i < 4160; i += 256) p0[i] = z;
    }
    __syncthreads();

    short8 afC[2][2], afN[2][2];
    // prologue: stage chunk 0 into buf 0, unit by unit (bounded registers)
    if (hValid) {
        float xg0[16];
#pragma unroll
        for (int g = 0; g < 4; ++g) { issueX(xg0, 0, g); writeX(xg0, g, 0); }
    }
    loadA(afC, 0, 0);
    LGKM0();
    BARRIER();

    f32x16 acc[2][4] = {};
    float xg[16]; // single staging slot: write(t-1) then issue(t) reuses it

    for (int c = 0; c < 8; ++c) {
        int buf = c & 1;
        bool stage = (c < 7) && hValid;
#pragma unroll
        for (int t = 0; t < 9; ++t) {
            bool lastTap = (c == 7 && t == 8);
            if (!lastTap)
                loadA(afN, t < 8 ? c : c + 1, t < 8 ? t + 1 : 0);
            if (stage) {
                if (t >= 1 && t < 5) writeX(xg, t - 1, buf ^ 1); // unit t-1
                if (t < 4)           issueX(xg, c + 1, t);       // unit t
            }

            int kh = t / 3, kw = t - kh * 3;
            short8 bx8[2][4];
#pragma unroll
            for (int kk = 0; kk < 2; ++kk)
#pragma unroll
                for (int ni = 0; ni < 4; ++ni)
                    bx8[kk][ni] = *reinterpret_cast<const short8*>(
                        &Xs[buf][wr + kh][kk * 2 + lh][ni * 32 + l31 + kw][0]);
            __builtin_amdgcn_s_setprio(1);
#pragma unroll
            for (int mi = 0; mi < 2; ++mi)
#pragma unroll
                for (int ni = 0; ni < 4; ++ni)
#pragma unroll
                    for (int kk = 0; kk < 2; ++kk)
                        acc[mi][ni] = __builtin_amdgcn_mfma_f32_32x32x16_bf16(
                            afC[kk][mi], bx8[kk][ni], acc[mi][ni], 0, 0, 0);
            __builtin_amdgcn_s_setprio(0);

            if (!lastTap) {
#pragma unroll
                for (int k2 = 0; k2 < 2; ++k2)
#pragma unroll
                    for (int mi = 0; mi < 2; ++mi)
                        afC[k2][mi] = afN[k2][mi];
            }
        }
        if (c < 7) { LGKM0(); BARRIER(); } // ds_writes of chunk c+1 visible block-wide
    }

    // epilogue: C/D 32x32 layout col=lane&31 (w), row=(reg&3)+8*(reg>>2)+4*(lane>>5) (o)
    int h = h0 + wr;
#pragma unroll
    for (int mi = 0; mi < 2; ++mi) {
        int ob = ot * 128 + wm * 64 + mi * 32 + 4 * lh;
#pragma unroll
        for (int ni = 0; ni < 4; ++ni) {
            int w_ = ni * 32 + l31;
#pragma unroll
            for (int reg = 0; reg < 16; ++reg) {
                int o = ob + (reg & 3) + 8 * (reg >> 2);
                out[(((size_t)(b * 256 + o) * 128 + h) * 128) + w_] = acc[mi][ni][reg];
            }
        }
    }
}

extern "C" void kernel_launch(void* const* d_in, const int* in_sizes, int n_in,
                              void* d_out, int out_size, void* d_ws, size_t ws_size,
                              hipStream_t stream) {
    const float* x        = (const float*)d_in[0];
    const float* w        = (const float*)d_in[1];
    const float* weight   = (const float*)d_in[2];
    const float* affine_w = (const float*)d_in[3];
    const float* affine_b = (const float*)d_in[4];
    float* out = (float*)d_out;

    float* style = (float*)d_ws;                                   // 8 KB
    u16* wgt = (u16*)((char*)d_ws + 8192);                         // 9.44 MB

    style_kernel<<<8, 256, 0, stream>>>(w, affine_w, affine_b, style);
    modw_kernel<<<2048, 256, 0, stream>>>(weight, style, wgt);
    conv_kernel<<<1024, 256, 0, stream>>>(x, wgt, out);
}